// Round 1
// 746.528 us; speedup vs baseline: 1.0044x; 1.0044x over previous
//
#include <hip/hip_runtime.h>
#include <math.h>

#define LL 8
#define G 17
#define NH 30
#define D 768
#define N 4096
#define CH 31              // NH+1
#define CELLS (G*G*G)      // 4913
#define CSTRIDE (CH*D)     // 23808 floats per cell
#define NBIN 16            // bins per axis (floor(p) in [0,15])
#define CPG 16
#define NCHUNK ((CELLS+CPG-1)/CPG)   // 308

__device__ __forceinline__ int iclip(int i){ return i<0?0:(i>G-1?G-1:i); }

// ---------------- K1: per-sample weights/indices, dist, bin histogram ----------------
__global__ void k_prep(const float* __restrict__ samples, const float* __restrict__ last_point,
                       float* __restrict__ wxyz, int* __restrict__ ixyz,
                       float* __restrict__ dist, int* __restrict__ sampleBin,
                       int* __restrict__ binCount){
    int s = blockIdx.x*blockDim.x + threadIdx.x;
    if (s >= N) return;
    float x0 = samples[s*3+0], y0 = samples[s*3+1], z0 = samples[s*3+2];
    float p[3] = {x0 + (float)LL, y0 + (float)LL, z0 + (float)LL};
    float fv[3], cv[3], dv[3]; int fi[3], ci[3];
    for (int a=0;a<3;a++){
        fv[a]=floorf(p[a]); cv[a]=ceilf(p[a]); dv[a]=p[a]-fv[a];
        fi[a]=(int)fv[a]; ci[a]=(int)cv[a];
    }
    {
        int fx=fi[0]; float dx=dv[0];
        float mlo=(fx>0)?1.f:0.f, mhi=(fx+2<G)?1.f:0.f;
        float cnt=2.f+mlo+mhi;
        float w[4]={(1.f-dx)*mlo/cnt,(2.f-dx)/cnt,(1.f+dx)/cnt,dx*mhi/cnt};
        int id[4]={iclip(fx-1),iclip(fx),iclip(fx+1),iclip(fx+2)};
        for(int i=0;i<4;i++){ wxyz[s*12+i]=w[i]; ixyz[s*12+i]=id[i]; }
    }
    {
        int fy=fi[1], cy=ci[1]; float dy=dv[1];
        float mlo=(fy>0)?1.f:0.f, mhi=(fy+2<G)?1.f:0.f;
        float cnt=2.f+mlo+mhi;
        float w[4]={(1.f-dy)*mlo/cnt,(2.f-dy)/cnt,(1.f+dy)/cnt,dy*mhi/cnt};
        int id[4]={iclip(fy-1),iclip(fy),iclip(cy),iclip(cy+1)};
        for(int i=0;i<4;i++){ wxyz[s*12+4+i]=w[i]; ixyz[s*12+4+i]=id[i]; }
    }
    {
        int fz=fi[2], cz=ci[2]; float dz=dv[2];
        float mlo=(fz>0)?1.f:0.f, mhi=(fz+2<G)?1.f:0.f;
        float cnt=2.f+mlo+mhi;
        float w[4]={(1.f-dz)*mlo/cnt,(2.f-dz)/cnt,(1.f+dz)/cnt,dz*mhi/cnt};
        int id[4]={iclip(fz-1),iclip(fz),iclip(cz),iclip(cz+1)};
        for(int i=0;i<4;i++){ wxyz[s*12+8+i]=w[i]; ixyz[s*12+8+i]=id[i]; }
    }
    float nx,ny,nz;
    if (s < N-1){ nx=samples[(s+1)*3+0]; ny=samples[(s+1)*3+1]; nz=samples[(s+1)*3+2]; }
    else        { nx=last_point[0];      ny=last_point[1];      nz=last_point[2]; }
    float ddx=x0-nx, ddy=y0-ny, ddz=z0-nz;
    dist[s]=sqrtf(ddx*ddx+ddy*ddy+ddz*ddz);
    int bx=min(max(fi[0],0),NBIN-1), by=min(max(fi[1],0),NBIN-1), bz=min(max(fi[2],0),NBIN-1);
    int bin=(bz*NBIN+by)*NBIN+bx;
    sampleBin[s]=bin;
    atomicAdd(&binCount[bin],1);
}

// ---------------- K1b: exclusive scan over 4096 bin counts (single block) ----------------
__global__ void k_binscan(const int* __restrict__ binCount, int* __restrict__ binStart,
                          int* __restrict__ binCursor){
    __shared__ int sh[256];
    __shared__ int srun;
    int t = threadIdx.x;
    if (t==0) srun=0;
    __syncthreads();
    for (int base=0; base<NBIN*NBIN*NBIN; base+=256){
        int v = binCount[base+t];
        sh[t]=v; __syncthreads();
        for (int off=1; off<256; off<<=1){
            int u = (t>=off)? sh[t-off] : 0;
            __syncthreads();
            sh[t]+=u;
            __syncthreads();
        }
        int incl = sh[t];
        int st = srun + incl - v;
        binStart[base+t]=st; binCursor[base+t]=st;
        __syncthreads();
        if (t==255) srun += incl;
        __syncthreads();
    }
}

// ---------------- K1c: scatter sample ids into bin order ----------------
__global__ void k_scatter(const int* __restrict__ sampleBin, int* __restrict__ binCursor,
                          int* __restrict__ binned){
    int s = blockIdx.x*blockDim.x + threadIdx.x;
    if (s>=N) return;
    int b=sampleBin[s];
    int pos=atomicAdd(&binCursor[b],1);
    binned[pos]=s;
}

// ---------------- K2: density[n,d] = sum_cells W * E[c,30,d] ----------------
// Compacted (weight, offset) list in LDS -> branch-free gather loop for load pipelining.
__global__ __launch_bounds__(192) void k_density(const float* __restrict__ emb,
                       const float* __restrict__ wxyz, const int* __restrict__ ixyz,
                       const int* __restrict__ binned,
                       float* __restrict__ density){
    int b = blockIdx.x;
    int s = binned[((b & 7) << 9) | (b >> 3)];   // N/8 = 512 per XCD chunk
    int t = threadIdx.x;
    __shared__ float w[12]; __shared__ int idx[12];
    __shared__ float lw[64]; __shared__ int loff[64];
    __shared__ int lcnt;
    if (t<12){ w[t]=wxyz[s*12+t]; idx[t]=ixyz[s*12+t]; }
    if (t==0) lcnt=0;
    __syncthreads();
    if (t < 64){
        int i = t>>4, j = (t>>2)&3, k = t&3;
        float www = w[i]*w[4+j]*w[8+k];
        if (www != 0.f){
            int pos = atomicAdd(&lcnt, 1);
            lw[pos]   = www;
            loff[pos] = ((idx[i]*G+idx[4+j])*G+idx[8+k])*CSTRIDE + NH*D;
        }
    }
    __syncthreads();
    int m = lcnt;
    float4 acc = make_float4(0.f,0.f,0.f,0.f);
    #pragma unroll 4
    for (int q=0;q<m;q++){
        const float4* p = (const float4*)(emb + (size_t)loff[q]);
        float4 v = p[t];
        float www = lw[q];
        acc.x += www*v.x; acc.y += www*v.y; acc.z += www*v.z; acc.w += www*v.w;
    }
    ((float4*)(density + (size_t)s*D))[t] = acc;
}

// ---------------- transpose RxC -> CxR (64x64 LDS tiles, block (64,4)) ----------------
__global__ void k_transpose(const float* __restrict__ in, float* __restrict__ out,
                            int R, int C){
    __shared__ float tile[64][65];
    int tx=threadIdx.x, ty=threadIdx.y;
    int c0=blockIdx.x*64, r0=blockIdx.y*64;
    #pragma unroll
    for (int k=0;k<16;k++){
        int r=r0+ty+k*4;
        tile[ty+k*4][tx] = in[(size_t)r*C + c0 + tx];
    }
    __syncthreads();
    #pragma unroll
    for (int k=0;k<16;k++){
        int c=c0+ty+k*4;
        out[(size_t)c*R + r0 + tx] = tile[tx][ty+k*4];
    }
}

// ---------------- K3: full-column scan, one block per column ----------------
#define SIDX(n) ((n) + ((n)>>4))
__global__ __launch_bounds__(256) void k_scan(const float* __restrict__ density_t,
                       const float* __restrict__ dist, float* __restrict__ wgt_t){
    __shared__ float buf[4096 + 256];
    __shared__ float wtot[4];
    int t = threadIdx.x;
    int d = blockIdx.x;
    const float* col = density_t + (size_t)d*N;
    float* out = wgt_t + (size_t)d*N;
    #pragma unroll
    for (int i=0;i<16;i++){
        int n = i*256 + t;
        buf[SIDX(n)] = fmaxf(col[n], 0.f) * dist[n];
    }
    __syncthreads();
    int lane = t & 63, wave = t >> 6;
    float vals[16]; float sum = 0.f;
    #pragma unroll
    for (int j=0;j<16;j++){ vals[j] = buf[SIDX(t*16+j)]; sum += vals[j]; }
    float x = sum;
    #pragma unroll
    for (int off=1; off<64; off<<=1){
        float u = __shfl_up(x, (unsigned)off, 64);
        if (lane >= off) x += u;
    }
    if (lane == 63) wtot[wave] = x;
    float thread_excl = x - sum;
    __syncthreads();
    float wexcl = 0.f;
    for (int w2=0; w2<4; w2++) if (w2 < wave) wexcl += wtot[w2];
    float run = wexcl + thread_excl;
    #pragma unroll
    for (int j=0;j<16;j++){
        float sd = vals[j];
        run += sd;                                   // inclusive cumsum
        buf[SIDX(t*16+j)] = expf(sd-run) - expf(-run); // T*alpha
    }
    __syncthreads();
    #pragma unroll
    for (int i=0;i<16;i++){
        int n = i*256 + t;
        out[n] = buf[SIDX(n)];
    }
}

// ---------------- K4: A[c,d] = sum_n W[n,c]*wgt[n,d] (LDS work-list per cell) ----------------
#define MAXS 1024
__global__ __launch_bounds__(192) void k_accumA(const float* __restrict__ wgt,
                       const float* __restrict__ wxyz, const int* __restrict__ ixyz,
                       const int* __restrict__ binStart, const int* __restrict__ binCount,
                       const int* __restrict__ binned, float* __restrict__ A){
    int b = blockIdx.x;
    int c = (b & 7) * 615 + (b >> 3);   // XCD-contiguous cell ranges
    if (c >= CELLS) return;
    int t = threadIdx.x;
    int x=c/(G*G); int rem=c-x*G*G; int y=rem/G; int z=rem-y*G;
    __shared__ int   ls[MAXS];
    __shared__ float lw[MAXS];
    __shared__ int   lcount;
    if (t==0) lcount = 0;
    __syncthreads();
    int bx0=max(0,x-2), bx1=min(NBIN-1,x+1);
    int by0=max(0,y-2), by1=min(NBIN-1,y+1);
    int bz0=max(0,z-2), bz1=min(NBIN-1,z+1);
    int nx=bx1-bx0+1, ny=by1-by0+1, nz=bz1-bz0+1;
    int nb = nx*ny*nz;
    for (int bi=t; bi<nb; bi+=192){
        int bxo = bi % nx; int r2 = bi / nx;
        int byo = r2 % ny; int bzo = r2 / ny;
        int bin = ((bz0+bzo)*NBIN + (by0+byo))*NBIN + (bx0+bxo);
        int st = binStart[bin], cnt = binCount[bin];
        for (int q=0;q<cnt;q++){
            int s = binned[st+q];
            const float* w = wxyz + (size_t)s*12;
            const int* id  = ixyz + (size_t)s*12;
            float px=0.f,py=0.f,pz=0.f;
            #pragma unroll
            for (int i=0;i<4;i++){
                px += (id[i]  ==x)? w[i]  :0.f;
                py += (id[4+i]==y)? w[4+i]:0.f;
                pz += (id[8+i]==z)? w[8+i]:0.f;
            }
            float wt = px*py*pz;
            if (wt != 0.f){
                int pos = atomicAdd(&lcount, 1);
                if (pos < MAXS){ ls[pos]=s; lw[pos]=wt; }
            }
        }
    }
    __syncthreads();
    int m = min(lcount, MAXS);
    float4 acc = make_float4(0.f,0.f,0.f,0.f);
    for (int i=0;i<m;i++){
        int s = ls[i]; float wt = lw[i];
        float4 v = ((const float4*)(wgt + (size_t)s*D))[t];
        acc.x += wt*v.x; acc.y += wt*v.y; acc.z += wt*v.z; acc.w += wt*v.w;
    }
    ((float4*)(A + (size_t)c*D))[t] = acc;
}

// ---------------- K5a: partial[chunk,h,d] = sum_{c in chunk} A[c,d]*E[c,h,d] ----------------
// float4 loads (16B/lane), h split into 3 groups of 10 via blockIdx.y, 192 threads cover D.
__global__ __launch_bounds__(192) void k_out(const float* __restrict__ emb,
                      const float* __restrict__ A, float* __restrict__ partial){
    int t = threadIdx.x;                 // d-quad index: d = 4t .. 4t+3
    int chunk = blockIdx.x;
    int h0 = blockIdx.y * 10;            // h-groups {0..9},{10..19},{20..29}
    int c0 = chunk*CPG;
    int c1 = min(CELLS, c0+CPG);
    float4 acc[10];
    #pragma unroll
    for (int h=0;h<10;h++) acc[h]=make_float4(0.f,0.f,0.f,0.f);
    for (int c=c0;c<c1;c++){
        float4 a = ((const float4*)(A + (size_t)c*D))[t];
        const float* ebase = emb + (size_t)c*CSTRIDE + (size_t)h0*D;
        #pragma unroll
        for (int h=0;h<10;h++){
            float4 v = ((const float4*)(ebase + (size_t)h*D))[t];
            acc[h].x += a.x*v.x; acc[h].y += a.y*v.y;
            acc[h].z += a.z*v.z; acc[h].w += a.w*v.w;
        }
    }
    float* pr = partial + (size_t)chunk*NH*D + (size_t)h0*D;
    #pragma unroll
    for (int h=0;h<10;h++)
        ((float4*)(pr + (size_t)h*D))[t] = acc[h];
}

// ---------------- K5b: out[i] += sum over chunk-group of partial ----------------
// 4 chunk-groups (blockIdx.y) of 77 chunks each; float4 loads; atomicAdd into zeroed out.
__global__ __launch_bounds__(256) void k_reduce(const float* __restrict__ partial,
                       float* __restrict__ out){
    int i = blockIdx.x*256 + threadIdx.x;   // float4 index into NH*D
    if (i >= NH*D/4) return;
    int cbeg = blockIdx.y * 77;
    int cend = min(NCHUNK, cbeg + 77);
    float4 s = make_float4(0.f,0.f,0.f,0.f);
    #pragma unroll 4
    for (int c=cbeg;c<cend;c++){
        float4 v = ((const float4*)(partial + (size_t)c*NH*D))[i];
        s.x+=v.x; s.y+=v.y; s.z+=v.z; s.w+=v.w;
    }
    atomicAdd(&out[i*4+0], s.x);
    atomicAdd(&out[i*4+1], s.y);
    atomicAdd(&out[i*4+2], s.z);
    atomicAdd(&out[i*4+3], s.w);
}

extern "C" void kernel_launch(void* const* d_in, const int* in_sizes, int n_in,
                              void* d_out, int out_size, void* d_ws, size_t ws_size,
                              hipStream_t stream){
    const float* samples   = (const float*)d_in[0];
    const float* last_point= (const float*)d_in[1];
    const float* emb       = (const float*)d_in[2];
    char* ws=(char*)d_ws;
    float* wxyz     =(float*)(ws + 0);
    int*   ixyz     =(int*)  (ws + 196608);
    float* dist     =(float*)(ws + 393216);
    int*   sampleBin=(int*)  (ws + 409600);
    int*   binCount =(int*)  (ws + 425984);
    int*   binStart =(int*)  (ws + 442368);
    int*   binCursor=(int*)  (ws + 458752);
    int*   binned   =(int*)  (ws + 475136);
    float* density  =(float*)(ws + 524288);               // 12.58 MB
    float* density_t=(float*)(ws + 524288 + 12582912);    // 12.58 MB
    float* wgt_t    =(float*)(ws + 524288 + 2*12582912);  // 12.58 MB
    float* wgt      = density;                            // alias: density dead after T1
    float* A        =(float*)(ws + 524288 + 3*12582912);  // 15.09 MB
    float* partial  =(float*)(ws + 524288 + 3*12582912 + 15093504); // 28.4 MB (308 chunks)

    hipMemsetAsync(binCount, 0, 4096*sizeof(int), stream);
    hipMemsetAsync(d_out, 0, NH*D*sizeof(float), stream);

    k_prep   <<<N/256, 256, 0, stream>>>(samples, last_point, wxyz, ixyz, dist, sampleBin, binCount);
    k_binscan<<<1, 256, 0, stream>>>(binCount, binStart, binCursor);
    k_scatter<<<N/256, 256, 0, stream>>>(sampleBin, binCursor, binned);
    k_density<<<N, 192, 0, stream>>>(emb, wxyz, ixyz, binned, density);
    dim3 tb(64,4);
    k_transpose<<<dim3(D/64, N/64), tb, 0, stream>>>(density, density_t, N, D);
    k_scan   <<<D, 256, 0, stream>>>(density_t, dist, wgt_t);
    k_transpose<<<dim3(N/64, D/64), tb, 0, stream>>>(wgt_t, wgt, D, N);
    k_accumA <<<8*615, 192, 0, stream>>>(wgt, wxyz, ixyz, binStart, binCount, binned, A);
    k_out    <<<dim3(NCHUNK, 3), 192, 0, stream>>>(emb, A, partial);
    k_reduce <<<dim3((NH*D/4+255)/256, 4), 256, 0, stream>>>(partial, (float*)d_out);
}